// Round 7
// baseline (1235.915 us; speedup 1.0000x reference)
//
#include <hip/hip_runtime.h>

// Problem constants (from reference)
#define T_STEPS 100
#define BATCH   32
#define NIN     512
#define NN      2048
#define AREAS   2

// ALPHA = float(np.exp(-1e-3/1e-2)); cast to f32 at use-site.
#define ALPHA_D 0.9048374180359595

// ---------------------------------------------------------------------------
// k0: Poisson input spikes for ALL timesteps. f32 compare semantics.
__global__ __launch_bounds__(256)
void k0_xi(const float* __restrict__ rates, const float* __restrict__ noise,
           float* __restrict__ outXi, unsigned* __restrict__ xi_mask)
{
    int el = blockIdx.x * 256 + threadIdx.x;      // exact grid: 1,638,400
    float r = rates[el], nz = noise[el];
    float p = __fmul_rn(r, 0.001f);
    int spike = (nz < p) ? 1 : 0;
    outXi[el] = (float)spike;
    if (spike) {
        int t = el >> 14;
        int b = (el >> 9) & 31;
        int i = el & (NIN - 1);
        atomicOr(&xi_mask[(t * 32 + b) * 16 + (i >> 5)], 1u << (i & 31));
    }
}

// ---------------------------------------------------------------------------
// k_ff: feedforward currents Iff[t][b][a][n], one block per (tb, a).
__global__ __launch_bounds__(256)
void k_ff(const float* __restrict__ Win, const unsigned* __restrict__ xi_mask,
          float* __restrict__ Iff)
{
    const int tb  = blockIdx.x;      // t*32+b
    const int a   = blockIdx.y;
    const int tid = threadIdx.x;     // cols [8*tid, 8*tid+8)

    __shared__ unsigned mws[16];
    if (tid < 16) mws[tid] = xi_mask[tb * 16 + tid];
    __syncthreads();

    const float* Wa = Win + ((size_t)a << 20) + (tid << 3);
    float4 A0 = {0,0,0,0}, A1 = {0,0,0,0};
    for (int w = 0; w < 16; ++w) {
        unsigned mw = mws[w];
        int base_i = w << 5;
        while (mw) {
            int i = base_i + (__ffs(mw) - 1);
            mw &= mw - 1;
            const float* rp = Wa + ((size_t)i << 11);
            float4 w0 = ((const float4*)rp)[0];
            float4 w1 = ((const float4*)rp)[1];
            A0.x += w0.x; A0.y += w0.y; A0.z += w0.z; A0.w += w0.w;
            A1.x += w1.x; A1.y += w1.y; A1.z += w1.z; A1.w += w1.w;
        }
    }
    float* op = Iff + (((size_t)tb * 2 + a) << 11) + (tid << 3);
    ((float4*)op)[0] = A0;
    ((float4*)op)[1] = A1;
}

// ---------------------------------------------------------------------------
#define OFF_OF(rr) ((((rr) >> 11) << 23) + (((rr) & 2047) << 11))

// issue 8 row-gathers (float4 each) for rows lp[0..7] into p[0..7]
__device__ __forceinline__ void issue8v(const float* __restrict__ Wa,
                                        const unsigned short* lp, float4* p)
{
    uint4 u = *(const uint4*)lp;
    p[0] = *(const float4*)(Wa + OFF_OF((int)(u.x & 0xffff)));
    p[1] = *(const float4*)(Wa + OFF_OF((int)(u.x >> 16)));
    p[2] = *(const float4*)(Wa + OFF_OF((int)(u.y & 0xffff)));
    p[3] = *(const float4*)(Wa + OFF_OF((int)(u.y >> 16)));
    p[4] = *(const float4*)(Wa + OFF_OF((int)(u.z & 0xffff)));
    p[5] = *(const float4*)(Wa + OFF_OF((int)(u.z >> 16)));
    p[6] = *(const float4*)(Wa + OFF_OF((int)(u.w & 0xffff)));
    p[7] = *(const float4*)(Wa + OFF_OF((int)(u.w >> 16)));
}

#define ACC4(P)  { acc.x = __fadd_rn(acc.x, (P).x); acc.y = __fadd_rn(acc.y, (P).y); \
                   acc.z = __fadd_rn(acc.z, (P).z); acc.w = __fadd_rn(acc.w, (P).w); }

// ---------------------------------------------------------------------------
// k_steps v7: 512 blocks = 32 batches x 16 slices, SINGLE-WAVE blocks
// (64 threads, float4/lane = 256 cols/block). Post-mortem chain:
//   R0 14.5 | R2 33.7 | v3 16.7 | v4 12.1 | v5 10.6 | v6 9.6 us/step.
// v6's VGPR=60 (<64 needed for two live 32-banks) proved sched_barrier
// cannot force depth. Fitting all points: loaded RT ~1.5us = 17x unloaded
// L2 latency -> TA-port queueing. A wave64 scattered load costs ~16 cyc of
// address processing (4 addr/cyc); v6 issued 8 waves/CU x 87 loads = 11k
// TA-cyc/step = 4.6us of port occupancy. v7 keeps bytes identical but
// quarters the ADDRESSES: 2 waves/CU x 87 wave-loads = 2784 TA-cyc
// (1.16us). Expected RT collapse -> gather ~2-3us/step.
// Single-wave block bonuses: __syncthreads lowers to waitcnt only (no
// s_barrier), scan/expand wave-synchronous. Per-col add chains remain
// STRICTLY ascending (s,n) serial __fadd_rn (same order as the passing R2
// float4 kernel) -- bit-exact. Sync = v5's data-is-the-barrier (epoch-
// tagged u64 masks, atomicExch publish at CP, coalesced sc1 poll).
__global__ __launch_bounds__(64, 1)
void k_steps(const float* __restrict__ Wrec,
             unsigned long long* __restrict__ smask,  // [2][B][128] u64 tag|mask
             const float* __restrict__ Iff,           // [t][b][a][n]
             float* __restrict__ outS)                // out + T*B*NIN
{
    const int lane = threadIdx.x;              // 0..63
    const int bx   = blockIdx.x;               // b*16 + s  (XCD = s%8)
    const int s    = bx & 15;
    const int b    = bx >> 4;
    const int a    = s >> 3;                   // dst area
    const int m0   = (s & 7) << 8;             // column-slice base
    const int c    = m0 + (lane << 2);         // this lane's 4 dst columns

    __shared__ unsigned mws[128];
    __shared__ __align__(16) unsigned short lrec[AREAS * NN];  // 8 KB
    __shared__ int base[128];
    __shared__ int cnt_rec;
    __shared__ unsigned nsp[8];

    const float* __restrict__ Wa = Wrec + ((size_t)a << 22) + c;
    const int rr_self = (a << 11) | c;
    const int wsel = rr_self >> 5;
    const int bsh  = rr_self & 31;             // nibble-aligned (c = 4*lane)
    const int w0   = s << 3;                   // this block's 8 owned words

    float4 vst = {0.f, 0.f, 0.f, 0.f};

    for (int t = 0; t < T_STEPS; ++t) {
        unsigned long long* cur = smask + (size_t)(t & 1) * (BATCH * 128) + (b << 7);
        unsigned long long* nxt = smask + (size_t)((t + 1) & 1) * (BATCH * 128) + (b << 7);

        // ---- phase 1: data-spin -- each lane polls TWO tagged words
        //      (coalesced sc1 loads; memset tag0 => step 0 passes at once)
        {
            unsigned long long v0 = __hip_atomic_load(&cur[lane], __ATOMIC_RELAXED,
                                                      __HIP_MEMORY_SCOPE_AGENT);
            while ((unsigned)(v0 >> 32) != (unsigned)t) {
                __builtin_amdgcn_s_sleep(2);
                v0 = __hip_atomic_load(&cur[lane], __ATOMIC_RELAXED,
                                       __HIP_MEMORY_SCOPE_AGENT);
            }
            unsigned long long v1 = __hip_atomic_load(&cur[lane + 64], __ATOMIC_RELAXED,
                                                      __HIP_MEMORY_SCOPE_AGENT);
            while ((unsigned)(v1 >> 32) != (unsigned)t) {
                __builtin_amdgcn_s_sleep(2);
                v1 = __hip_atomic_load(&cur[lane + 64], __ATOMIC_RELAXED,
                                       __HIP_MEMORY_SCOPE_AGENT);
            }
            mws[lane]      = (unsigned)v0;
            mws[lane + 64] = (unsigned)v1;
        }
        if (lane < 8) nsp[lane] = 0u;
        float4 accf = *(const float4*)
            &Iff[((((size_t)t * BATCH + b) * 2 + a) << 11) + c];
        __syncthreads();   // 1-wave workgroup: lowers to lgkmcnt wait only

        // ---- phase 2: wave prefix scan of mask popcounts (2 words/lane)
        {
            int c0 = __popc(mws[2 * lane]), c1 = __popc(mws[2 * lane + 1]);
            int cc = c0 + c1, incl = cc;
            #pragma unroll
            for (int d = 1; d < 64; d <<= 1) {
                int v = __shfl_up(incl, d, 64);
                if (lane >= d) incl += v;
            }
            base[2 * lane]     = incl - cc;
            base[2 * lane + 1] = incl - c1;
            if (lane == 63) cnt_rec = incl;
        }
        __syncthreads();

        // ---- phase 3: expand mask to ascending row list (2 words/lane)
        {
            unsigned w = mws[2 * lane];
            int off = base[2 * lane];
            int bb = (2 * lane) << 5;
            while (w) { int p = __ffs(w) - 1; lrec[off++] = (unsigned short)(bb + p); w &= w - 1; }
            w = mws[2 * lane + 1];
            off = base[2 * lane + 1];
            bb = (2 * lane + 1) << 5;
            while (w) { int p = __ffs(w) - 1; lrec[off++] = (unsigned short)(bb + p); w &= w - 1; }
        }
        __syncthreads();

        const int nrec = cnt_rec;
        unsigned xw = (mws[wsel] >> bsh) & 0xFu;

        // ---- phase 4: recurrent gather, 16-row float4 ping-pong banks,
        //      ascending rows, serial f32 adds per column (bit-exact) ----
        float4 acc = {0.f, 0.f, 0.f, 0.f};
        int j = 0;
        if (nrec >= 16) {
            float4 p[16], q[16];
            issue8v(Wa, &lrec[0], p); issue8v(Wa, &lrec[8], p + 8);
            j = 16;
            while (j + 32 <= nrec) {           // steady: 32 rows/iter
                issue8v(Wa, &lrec[j], q); issue8v(Wa, &lrec[j + 8], q + 8);
                __builtin_amdgcn_sched_barrier(0);
                #pragma unroll
                for (int k = 0; k < 16; ++k) ACC4(p[k]);
                issue8v(Wa, &lrec[j + 16], p); issue8v(Wa, &lrec[j + 24], p + 8);
                __builtin_amdgcn_sched_barrier(0);
                #pragma unroll
                for (int k = 0; k < 16; ++k) ACC4(q[k]);
                j += 32;
            }
            if (j + 16 <= nrec) {              // one extra 16-bank
                issue8v(Wa, &lrec[j], q); issue8v(Wa, &lrec[j + 8], q + 8);
                __builtin_amdgcn_sched_barrier(0);
                #pragma unroll
                for (int k = 0; k < 16; ++k) ACC4(p[k]);
                #pragma unroll
                for (int k = 0; k < 16; ++k) p[k] = q[k];
                j += 16;
            }
            #pragma unroll
            for (int k = 0; k < 16; ++k) ACC4(p[k]);
        }
        if (nrec - j >= 8) {                   // 8-deep mid stage (<16 left)
            float4 p8[8];
            issue8v(Wa, &lrec[j], p8);
            #pragma unroll
            for (int k = 0; k < 8; ++k) ACC4(p8[k]);
            j += 8;
        }
        for (; j < nrec; ++j) {                // scalar tail (<8 left)
            float4 pr = *(const float4*)(Wa + OFF_OF((int)lrec[j]));
            ACC4(pr);
        }

        // ---- phase 5: LIF update, numpy f32 op-for-op ----
        float4 sv;
        unsigned nib = 0u;
#define LIF(K, BIT) { \
            float v  = __fmul_rn((float)ALPHA_D, vst.K); \
            if (xw & BIT) v = 0.0f; \
            float I  = __fadd_rn(accf.K, acc.K); \
            float vn = __fadd_rn(v, I); \
            vst.K = vn; \
            if (vn >= 1.0f) { sv.K = 1.0f; nib |= BIT; } else sv.K = 0.0f; \
        }
        LIF(x, 1u) LIF(y, 2u) LIF(z, 4u) LIF(w, 8u)
#undef LIF
        if (nib) atomicOr(&nsp[lane >> 3], nib << ((lane & 7) << 2));
        __syncthreads();                       // nsp complete (waitcnt only)

        // ---- phase 6: publish tagged words FIRST, then outS store
        if (t < T_STEPS - 1 && lane < 8) {
            unsigned long long pv =
                ((unsigned long long)(unsigned)(t + 1) << 32) | nsp[lane];
            atomicExch(&nxt[w0 + lane], pv);   // RMW executes at CP (m20)
        }
        *(float4*)&outS[(size_t)a * (T_STEPS * BATCH * NN)
                        + (((size_t)t * BATCH + b) << 11) + c] = sv;
    }
}
#undef OFF_OF
#undef ACC4

// ---------------------------------------------------------------------------
extern "C" void kernel_launch(void* const* d_in, const int* in_sizes, int n_in,
                              void* d_out, int out_size, void* d_ws, size_t ws_size,
                              hipStream_t stream)
{
    const float* rates = (const float*)d_in[0];
    const float* noise = (const float*)d_in[1];
    const float* Win   = (const float*)d_in[2];
    const float* Wrec  = (const float*)d_in[3];
    float* out = (float*)d_out;

    // workspace layout (bytes):
    //   [0, 204800)           xi_mask uint32[T][B][16]
    //   [204800, 270336)      smask   u64[2][B][128]  (tag<<32 | mask)
    //   [270336, +52428800)   Iff     float[T][B][A][N]  (16B aligned)
    char* ws = (char*)d_ws;
    unsigned* xi_mask = (unsigned*)ws;
    unsigned long long* smask = (unsigned long long*)(ws + 204800);
    float* Iff = (float*)(ws + 270336);

    hipMemsetAsync(d_ws, 0, 270336, stream);   // zero xi_mask + smask

    k0_xi<<<6400, 256, 0, stream>>>(rates, noise, out, xi_mask);
    k_ff<<<dim3(3200, 2), 256, 0, stream>>>(Win, xi_mask, Iff);

    float* outS = out + (size_t)T_STEPS * BATCH * NIN;
    void* args[] = { (void*)&Wrec, (void*)&smask, (void*)&Iff, (void*)&outS };
    hipLaunchCooperativeKernel((const void*)k_steps, dim3(512), dim3(64),
                               args, 0, stream);
}